// Round 9
// baseline (597.615 us; speedup 1.0000x reference)
//
#include <hip/hip_runtime.h>
#include <hip/hip_bf16.h>

// Mamba2 layer, MI355X/gfx950. Round 8: XOR k-slot LDS swizzle in both GEMMs
// (kills the constant 1.756e7 bank-conflict cycles: 8-way -> 2-way=free), and
// gemm2 upgraded to 256x128/512t + XCD swizzle (gemm1's proven config).

#define D_MODEL   2048
#define D_STATE   128
#define HEADDIM   64
#define CHUNK     256
#define D_INNER   4096
#define NHEADS    64
#define CONV_DIM  4352
#define D_IN_PROJ 8512
#define SEQLEN    2048
#define NC        8
#define ROWSTOT   4096
#define NPAD      8576
#define RMS_EPS   1e-5f

// ---- workspace layout (byte offsets), lifetime-overlaid ----
// S_A: win_bf(steps 0-1) -> x_bf(4-6) -> prevb(7-8)@+0 ; wout_bf(9-11)@+16MB
#define OFF_WIN   0ull
#define OFF_XBF   0ull
#define OFF_PREV  0ull
#define OFF_WOUT  16777216ull
#define OFF_UBF   35127296ull
#define OFF_DTV   35127296ull
#define OFF_DACS  36175872ull
#define OFF_BBF   37224448ull
#define OFF_CBF   38273024ull
#define OFF_CB    39321600ull
#define OFF_BT    43515904ull
#define OFF_XBC   51904512ull
#define OFF_STATE 51904512ull
#define OFF_ZBF   87556096ull
#define OFF_DTRAW 121110528ull
#define OFF_YBUF  121110528ull
#define WS_NEEDED 154664960ull

// fused-cast segment sizes (float4 units) — u and w_in ONLY
#define N4_U    2097152l
#define N4_WIN  4390912l

typedef __hip_bfloat16 bf16;
typedef __bf16 bfrag8 __attribute__((ext_vector_type(8)));
typedef float  f32x4v __attribute__((ext_vector_type(4)));

__device__ __forceinline__ f32x4v mfma16(bfrag8 a, bfrag8 b, f32x4v c) {
  return __builtin_amdgcn_mfma_f32_16x16x32_bf16(a, b, c, 0, 0, 0);
}

__device__ __forceinline__ void gload_lds16(const void* g, void* l) {
  __builtin_amdgcn_global_load_lds((const __attribute__((address_space(1))) void*)g,
                                   (__attribute__((address_space(3))) void*)l, 16, 0, 0);
}

__device__ __forceinline__ bf16 f2b(float x) { return __float2bfloat16(x); }
__device__ __forceinline__ float b2f(bf16 x) { return __bfloat162float(x); }
__device__ __forceinline__ float siluf(float x) { return x / (1.f + __expf(-x)); }

// ---------------- cast: u -> u_bf, w_in -> win_bf (padded). NOT w_out. ------
__global__ __launch_bounds__(256) void cast_all_kernel(const float* __restrict__ u,
    const float* __restrict__ w_in,
    bf16* __restrict__ u_bf, bf16* __restrict__ win_bf) {
  long i = (long)blockIdx.x * 256 + threadIdx.x;
  if (i < N4_U) {
    float4 v = ((const float4*)u)[i];
    bf16* o = u_bf + i * 4;
    o[0] = f2b(v.x); o[1] = f2b(v.y); o[2] = f2b(v.z); o[3] = f2b(v.w);
  } else if (i < N4_U + N4_WIN) {
    long e = (i - N4_U) * 4;
    long row = e / D_MODEL;
    bf16* o = win_bf + e;
    if (row < D_IN_PROJ) {
      float4 v = *(const float4*)(w_in + e);
      o[0] = f2b(v.x); o[1] = f2b(v.y); o[2] = f2b(v.z); o[3] = f2b(v.w);
    } else {
      bf16 z = f2b(0.f);
      o[0] = z; o[1] = z; o[2] = z; o[3] = z;
    }
  }
}

// ---------------- simple cast (for w_out, launched late) --------------------
__global__ __launch_bounds__(256) void cast_kernel(const float* __restrict__ in,
                                                   bf16* __restrict__ out, long n4) {
  long i = (long)blockIdx.x * 256 + threadIdx.x;
  if (i >= n4) return;
  float4 v = ((const float4*)in)[i];
  bf16* o = out + i * 4;
  o[0] = f2b(v.x); o[1] = f2b(v.y); o[2] = f2b(v.z); o[3] = f2b(v.w);
}

// LDS swizzle: k-slot q of row r stored at slot q^((r>>1)&3). Staging applies
// the permute on the GLOBAL k-offset; frag reads use (q^((r16>>1)&3))*8.
// Result: every bank 8 dwords/wave-instr (2-way aliasing = free, m136).

// ---------------- GEMM1: 256x128 tile, 512 threads, BK=64, XCD swizzle ------
__global__ __launch_bounds__(512) void gemm1_kernel(const bf16* __restrict__ A,
                                                    const bf16* __restrict__ B,
                                                    bf16* __restrict__ zb,
                                                    bf16* __restrict__ xbc,
                                                    float* __restrict__ dtraw) {
  int pid = blockIdx.x;
  int t = pid & 63, s = pid >> 6;
  int sm = s / 9, sn = s % 9;
  int xcd = t & 7, j8 = t >> 3;
  int tm = sm * 8 + (xcd >> 1) * 2 + (j8 & 1);
  int tn = sn * 8 + (xcd & 1) * 4 + (j8 >> 1);
  if (tn >= 67) return;
  long row0 = (long)tm * 256, col0 = (long)tn * 128;

  __shared__ __align__(16) bf16 As[2 * 256 * 32];   // 32 KB
  __shared__ __align__(16) bf16 Bs[2 * 128 * 32];   // 16 KB
  int tid = threadIdx.x, lane = tid & 63, w = tid >> 6;
  int wr = w >> 1, wc = w & 1, r16 = lane & 15, q = lane >> 4;
  int qs = (q ^ ((r16 >> 1) & 3)) * 8;              // swizzled frag k-offset
  const int K = D_MODEL;
  f32x4v zero4 = {0.f, 0.f, 0.f, 0.f};
  f32x4v acc[4][4];
#pragma unroll
  for (int i = 0; i < 4; ++i)
#pragma unroll
    for (int j = 0; j < 4; ++j) acc[i][j] = zero4;

  for (int kt = 0; kt < K; kt += 64) {
    __syncthreads();
#pragma unroll
    for (int j = 0; j < 4; ++j) {          // A: 2048 chunks of 16B
      int ci = j * 512 + tid;
      int half = ci >> 10, cj = ci & 1023;
      int r = cj >> 2;
      int ko = half * 32 + ((cj & 3) ^ ((cj >> 3) & 3)) * 8;   // slot^((r>>1)&3)
      gload_lds16(A + (row0 + r) * (long)K + kt + ko,
                  (char*)As + j * 8192 + w * 1024);            // wave-uniform
    }
#pragma unroll
    for (int j = 0; j < 2; ++j) {          // B: 1024 chunks of 16B
      int ci = j * 512 + tid;
      int half = ci >> 9, cj = ci & 511;
      int r = cj >> 2;
      int ko = half * 32 + ((cj & 3) ^ ((cj >> 3) & 3)) * 8;
      gload_lds16(B + (col0 + r) * (long)K + kt + ko,
                  (char*)Bs + j * 8192 + w * 1024);            // wave-uniform
    }
    __syncthreads();
#pragma unroll
    for (int ks = 0; ks < 2; ++ks) {
      const bf16* Ab = As + ks * 8192;
      const bf16* Bb = Bs + ks * 4096;
      bfrag8 af[4], bfv[4];
#pragma unroll
      for (int i = 0; i < 4; ++i) af[i]  = *(const bfrag8*)(Ab + (wr * 64 + i * 16 + r16) * 32 + qs);
#pragma unroll
      for (int i = 0; i < 4; ++i) bfv[i] = *(const bfrag8*)(Bb + (wc * 64 + i * 16 + r16) * 32 + qs);
#pragma unroll
      for (int i = 0; i < 4; ++i)
#pragma unroll
        for (int j = 0; j < 4; ++j) acc[i][j] = mfma16(af[i], bfv[j], acc[i][j]);
    }
  }
#pragma unroll
  for (int i = 0; i < 4; ++i)
#pragma unroll
    for (int j = 0; j < 4; ++j) {
      long col = col0 + wc * 64 + j * 16 + r16;
#pragma unroll
      for (int r = 0; r < 4; ++r) {
        long row = row0 + wr * 64 + i * 16 + q * 4 + r;
        float v = acc[i][j][r];
        if (col < D_INNER)                       zb[row * D_INNER + col] = f2b(v);
        else if (col < D_INNER + CONV_DIM)       xbc[row * CONV_DIM + (col - D_INNER)] = f2b(v);
        else if (col < D_IN_PROJ)                dtraw[row * NHEADS + (col - D_INNER - CONV_DIM)] = v;
      }
    }
}

// ---------------- GEMM2: 256x128 tile, 512 threads, BK=64, XCD swizzle ------
__global__ __launch_bounds__(512) void gemm2_kernel(const bf16* __restrict__ A,
                                                    const bf16* __restrict__ B,
                                                    float* __restrict__ C) {
  int pid = blockIdx.x;
  int t = pid & 63, s = pid >> 6;          // tiles 16x16, super grid 2x2
  int sm = s >> 1, sn = s & 1;
  int xcd = t & 7, j8 = t >> 3;
  int tm = sm * 8 + (xcd >> 1) * 2 + (j8 & 1);
  int tn = sn * 8 + (xcd & 1) * 4 + (j8 >> 1);
  long row0 = (long)tm * 256, col0 = (long)tn * 128;

  __shared__ __align__(16) bf16 As[2 * 256 * 32];
  __shared__ __align__(16) bf16 Bs[2 * 128 * 32];
  int tid = threadIdx.x, lane = tid & 63, w = tid >> 6;
  int wr = w >> 1, wc = w & 1, r16 = lane & 15, q = lane >> 4;
  int qs = (q ^ ((r16 >> 1) & 3)) * 8;
  const int K = D_INNER, ldc = D_MODEL;
  f32x4v zero4 = {0.f, 0.f, 0.f, 0.f};
  f32x4v acc[4][4];
#pragma unroll
  for (int i = 0; i < 4; ++i)
#pragma unroll
    for (int j = 0; j < 4; ++j) acc[i][j] = zero4;

  for (int kt = 0; kt < K; kt += 64) {
    __syncthreads();
#pragma unroll
    for (int j = 0; j < 4; ++j) {          // A: 2048 chunks
      int ci = j * 512 + tid;
      int half = ci >> 10, cj = ci & 1023;
      int r = cj >> 2;
      int ko = half * 32 + ((cj & 3) ^ ((cj >> 3) & 3)) * 8;
      gload_lds16(A + (row0 + r) * (long)K + kt + ko,
                  (char*)As + j * 8192 + w * 1024);
    }
#pragma unroll
    for (int j = 0; j < 2; ++j) {          // B: 1024 chunks
      int ci = j * 512 + tid;
      int half = ci >> 9, cj = ci & 511;
      int r = cj >> 2;
      int ko = half * 32 + ((cj & 3) ^ ((cj >> 3) & 3)) * 8;
      gload_lds16(B + (col0 + r) * (long)K + kt + ko,
                  (char*)Bs + j * 8192 + w * 1024);
    }
    __syncthreads();
#pragma unroll
    for (int ks = 0; ks < 2; ++ks) {
      const bf16* Ab = As + ks * 8192;
      const bf16* Bb = Bs + ks * 4096;
      bfrag8 af[4], bfv[4];
#pragma unroll
      for (int i = 0; i < 4; ++i) af[i]  = *(const bfrag8*)(Ab + (wr * 64 + i * 16 + r16) * 32 + qs);
#pragma unroll
      for (int i = 0; i < 4; ++i) bfv[i] = *(const bfrag8*)(Bb + (wc * 64 + i * 16 + r16) * 32 + qs);
#pragma unroll
      for (int i = 0; i < 4; ++i)
#pragma unroll
        for (int j = 0; j < 4; ++j) acc[i][j] = mfma16(af[i], bfv[j], acc[i][j]);
    }
  }
#pragma unroll
  for (int i = 0; i < 4; ++i)
#pragma unroll
    for (int j = 0; j < 4; ++j)
#pragma unroll
      for (int r = 0; r < 4; ++r) {
        long row = row0 + wr * 64 + i * 16 + q * 4 + r;
        long col = col0 + wc * 64 + j * 16 + r16;
        C[row * ldc + col] = acc[i][j][r];
      }
}

// ---------------- dt softplus + per-chunk cumsum (shfl scan) ----------------
__global__ __launch_bounds__(256) void dt_scan_kernel(const float* __restrict__ dtraw,
    const float* __restrict__ dt_bias, const float* __restrict__ A_log,
    float* __restrict__ dtv_buf, float* __restrict__ dacs_buf) {
  int blk = blockIdx.x;
  int c = blk & 7, h = (blk >> 3) & 63, b = blk >> 9;
  int s = threadIdx.x, lane = s & 63, w = s >> 6;
  long row = (long)b * SEQLEN + c * CHUNK + s;
  float raw = dtraw[row * NHEADS + h] + dt_bias[h];
  float dtv = fmaxf(raw, 0.f) + log1pf(__expf(-fabsf(raw)));
  float A = -__expf(A_log[h]);
  float x = dtv * A;
#pragma unroll
  for (int off = 1; off < 64; off <<= 1) {
    float y = __shfl_up(x, off);
    if (lane >= off) x += y;
  }
  __shared__ __align__(16) float wsum[4];
  if (lane == 63) wsum[w] = x;
  __syncthreads();
  float pre = 0.f;
#pragma unroll
  for (int i = 0; i < 4; ++i) pre += (i < w) ? wsum[i] : 0.f;
  long o = ((long)(b * NHEADS + h) * NC + c) * CHUNK + s;
  dtv_buf[o] = dtv;
  dacs_buf[o] = x + pre;
}

// ---------------- conv1d + SiLU: 8 l per thread, sliding window -------------
__global__ __launch_bounds__(256) void conv_kernel(const bf16* __restrict__ xbc,
    const float* __restrict__ conv_w, const float* __restrict__ conv_b,
    bf16* __restrict__ xo, bf16* __restrict__ Bo, bf16* __restrict__ Co,
    bf16* __restrict__ BT) {
  int cidx = blockIdx.x * 256 + threadIdx.x;
  int l0 = blockIdx.y * 8, b = blockIdx.z;
  float4 wv = *(const float4*)(conv_w + cidx * 4);
  float bias = conv_b[cidx];
  const bf16* base = xbc + (long)b * SEQLEN * CONV_DIM + cidx;
  float win[11];
#pragma unroll
  for (int k = 0; k < 11; ++k) {
    int ls = l0 - 3 + k;
    win[k] = (ls >= 0) ? b2f(base[(long)ls * CONV_DIM]) : 0.f;
  }
  int cgrp = (cidx < D_INNER) ? 0 : ((cidx < D_INNER + D_STATE) ? 1 : 2);
  int n = cidx - D_INNER;
  int n2 = cidx - D_INNER - D_STATE;
  int cch = l0 >> 8;
#pragma unroll
  for (int j = 0; j < 8; ++j) {
    float acc = bias + wv.x * win[j] + wv.y * win[j + 1] + wv.z * win[j + 2] + wv.w * win[j + 3];
    bf16 o = f2b(siluf(acc));
    int l = l0 + j;
    long rowo = (long)b * SEQLEN + l;
    if (cgrp == 0) {
      xo[rowo * D_INNER + cidx] = o;
    } else if (cgrp == 1) {
      Bo[rowo * D_STATE + n] = o;
      BT[(((long)b * NC + cch) * D_STATE + n) * CHUNK + (l & 255)] = o;
    } else {
      Co[rowo * D_STATE + n2] = o;
    }
  }
}

// ---------------- CB[l,s] per (b,chunk), 4 st-tiles per block ----------------
__global__ __launch_bounds__(256) void cb_kernel(const bf16* __restrict__ Cg,
                                                 const bf16* __restrict__ Bg,
                                                 float* __restrict__ CB) {
  int blk = blockIdx.x;
  int stile = blk & 3, bc = blk >> 2;
  int c = bc & 7, b = bc >> 3;
  int tid = threadIdx.x, lane = tid & 63, w = tid >> 6, r16 = lane & 15, q = lane >> 4;
  const bf16* Cb = Cg + ((long)b * SEQLEN + c * CHUNK) * D_STATE;
  const bf16* Bb = Bg + ((long)b * SEQLEN + c * CHUNK) * D_STATE;
  bfrag8 af[4][4];
#pragma unroll
  for (int lt = 0; lt < 4; ++lt)
#pragma unroll
    for (int kk = 0; kk < 4; ++kk)
      af[lt][kk] = *(const bfrag8*)(Cb + (long)(w * 64 + lt * 16 + r16) * D_STATE + kk * 32 + q * 8);
  float* CBb = CB + (long)bc * CHUNK * CHUNK;
  f32x4v zero4 = {0.f, 0.f, 0.f, 0.f};
  for (int st = stile * 4; st < stile * 4 + 4; ++st) {
    f32x4v acc[4] = {zero4, zero4, zero4, zero4};
#pragma unroll
    for (int kk = 0; kk < 4; ++kk) {
      bfrag8 bfv = *(const bfrag8*)(Bb + (long)(st * 16 + r16) * D_STATE + kk * 32 + q * 8);
#pragma unroll
      for (int lt = 0; lt < 4; ++lt) acc[lt] = mfma16(af[lt][kk], bfv, acc[lt]);
    }
#pragma unroll
    for (int lt = 0; lt < 4; ++lt)
#pragma unroll
      for (int r = 0; r < 4; ++r)
        CBb[(long)(w * 64 + lt * 16 + q * 4 + r) * CHUNK + st * 16 + r16] = acc[lt][r];
  }
}

// ---------------- per (b,chunk,head): Y_diag + skip, chunk states ------------
__global__ __launch_bounds__(256) void ssm_diag_kernel(
    const bf16* __restrict__ xg, const bf16* __restrict__ BT,
    const float* __restrict__ CB, const float* __restrict__ dtv_buf,
    const float* __restrict__ dacs_buf, const float* __restrict__ Dskip,
    bf16* __restrict__ ybuf, float* __restrict__ states) {
  int blk = blockIdx.x;
  int h = blk & 63, cc = (blk >> 6) & 7, b = blk >> 9;
  int tid = threadIdx.x, lane = tid & 63, w = tid >> 6, r16 = lane & 15, q = lane >> 4;

  __shared__ __align__(16) __bf16 xT[HEADDIM][264];
  __shared__ __align__(16) float cs_s[CHUNK];
  __shared__ __align__(16) float dt_s[CHUNK];
  __shared__ __align__(16) float w_s[CHUNK];

  long hco = ((long)(b * NHEADS + h) * NC + cc) * CHUNK;
  cs_s[tid] = dacs_buf[hco + tid];
  dt_s[tid] = dtv_buf[hco + tid];
  __syncthreads();
  float cl_last = cs_s[CHUNK - 1];
  w_s[tid] = __expf(cl_last - cs_s[tid]) * dt_s[tid];

  const __bf16* xbase = (const __bf16*)(xg + ((long)b * SEQLEN + cc * CHUNK) * D_INNER + h * HEADDIM);
#pragma unroll
  for (int it = 0; it < 8; ++it) {
    int e = it * 256 + tid;
    int s = e >> 3, p0 = (e & 7) * 8;
    bfrag8 xv = *(const bfrag8*)(xbase + (long)s * D_INNER + p0);
#pragma unroll
    for (int j = 0; j < 8; ++j) xT[p0 + j][s] = xv[j];
  }
  __syncthreads();

  const float* CBchunk = CB + (long)(b * NC + cc) * CHUNK * CHUNK;
  const __bf16* BTc = (const __bf16*)(BT + (((long)b * NC + cc) * D_STATE) * CHUNK);
  f32x4v zero4 = {0.f, 0.f, 0.f, 0.f};
  f32x4v accY[4][4], accS[2][4];
#pragma unroll
  for (int i = 0; i < 4; ++i)
#pragma unroll
    for (int j = 0; j < 4; ++j) accY[i][j] = zero4;
#pragma unroll
  for (int i = 0; i < 2; ++i)
#pragma unroll
    for (int j = 0; j < 4; ++j) accS[i][j] = zero4;

  int l_row[4];
  const float* CBrow[4];
#pragma unroll
  for (int lt = 0; lt < 4; ++lt) {
    l_row[lt] = w * 64 + lt * 16 + r16;
    CBrow[lt] = CBchunk + (long)l_row[lt] * CHUNK;
  }

#pragma unroll 2
  for (int ks = 0; ks < 8; ++ks) {
    int s0 = ks * 32 + q * 8;
    float4 cs0 = *(const float4*)(cs_s + s0);
    float4 cs1 = *(const float4*)(cs_s + s0 + 4);
    float4 dt0 = *(const float4*)(dt_s + s0);
    float4 dt1 = *(const float4*)(dt_s + s0 + 4);
    float4 w0  = *(const float4*)(w_s + s0);
    float4 w1  = *(const float4*)(w_s + s0 + 4);
    float csv[8] = {cs0.x, cs0.y, cs0.z, cs0.w, cs1.x, cs1.y, cs1.z, cs1.w};
    float dtv8[8] = {dt0.x, dt0.y, dt0.z, dt0.w, dt1.x, dt1.y, dt1.z, dt1.w};
    float wv8[8]  = {w0.x, w0.y, w0.z, w0.w, w1.x, w1.y, w1.z, w1.w};

    bfrag8 xf[4];
#pragma unroll
    for (int pt = 0; pt < 4; ++pt) xf[pt] = *(const bfrag8*)(&xT[pt * 16 + r16][s0]);

#pragma unroll
    for (int lt = 0; lt < 4; ++lt) {
      int l = l_row[lt];
      float cs_l = cs_s[l];
      float4 cb0 = *(const float4*)(CBrow[lt] + s0);
      float4 cb1 = *(const float4*)(CBrow[lt] + s0 + 4);
      float cbv[8] = {cb0.x, cb0.y, cb0.z, cb0.w, cb1.x, cb1.y, cb1.z, cb1.w};
      bfrag8 pf;
#pragma unroll
      for (int j = 0; j < 8; ++j) {
        float v = (s0 + j <= l)
                    ? cbv[j] * __expf(fminf(cs_l - csv[j], 0.f)) * dtv8[j]
                    : 0.f;
        pf[j] = (__bf16)v;
      }
#pragma unroll
      for (int pt = 0; pt < 4; ++pt) accY[lt][pt] = mfma16(pf, xf[pt], accY[lt][pt]);
    }

#pragma unroll
    for (int nt = 0; nt < 2; ++nt) {
      int n = w * 32 + nt * 16 + r16;
      bfrag8 braw = *(const bfrag8*)(BTc + (long)n * CHUNK + s0);
      bfrag8 bwf;
#pragma unroll
      for (int j = 0; j < 8; ++j) bwf[j] = (__bf16)((float)braw[j] * wv8[j]);
#pragma unroll
      for (int pt = 0; pt < 4; ++pt) accS[nt][pt] = mfma16(bwf, xf[pt], accS[nt][pt]);
    }
  }

  float dsk = Dskip[h];
  bf16* ybase = ybuf + ((long)b * SEQLEN + cc * CHUNK) * D_INNER + h * HEADDIM;
#pragma unroll
  for (int lt = 0; lt < 4; ++lt)
#pragma unroll
    for (int pt = 0; pt < 4; ++pt)
#pragma unroll
      for (int r = 0; r < 4; ++r) {
        int lrow = w * 64 + lt * 16 + q * 4 + r;
        int pcol = pt * 16 + r16;
        ybase[(long)lrow * D_INNER + pcol] = f2b(accY[lt][pt][r] + (float)xT[pcol][lrow] * dsk);
      }
  float* sbase = states + (long)blk * (HEADDIM * D_STATE);
#pragma unroll
  for (int nt = 0; nt < 2; ++nt)
#pragma unroll
    for (int pt = 0; pt < 4; ++pt)
#pragma unroll
      for (int r = 0; r < 4; ++r)
        sbase[(long)(pt * 16 + r16) * D_STATE + w * 32 + nt * 16 + q * 4 + r] = accS[nt][pt][r];
}

// ---------------- inter-chunk state scan (e-parallel grid) ----------------
__global__ __launch_bounds__(256) void state_scan_kernel(const float* __restrict__ states,
    const float* __restrict__ dacs, bf16* __restrict__ prevb) {
  int gid = blockIdx.x;
  int et = gid & 31, bh = gid >> 5;
  int h = bh & 63, b = bh >> 6;
  int e = et * 256 + threadIdx.x;
  float dec[NC];
#pragma unroll
  for (int c = 0; c < NC; ++c)
    dec[c] = __expf(dacs[((long)(b * NHEADS + h) * NC + c) * CHUNK + (CHUNK - 1)]);
  float carry = 0.f;
#pragma unroll
  for (int c = 0; c < NC; ++c) {
    long off = ((long)((b * NC + c) * NHEADS + h)) * (HEADDIM * D_STATE) + e;
    prevb[off] = f2b(carry);
    carry = carry * dec[c] + states[off];
  }
}

// ---------------- Y_off accumulate (bf16 RMW) ----------------
__global__ __launch_bounds__(256) void yoff_kernel(const bf16* __restrict__ Cg,
    const bf16* __restrict__ prevb, const float* __restrict__ dacs,
    bf16* __restrict__ ybuf) {
  int blk = blockIdx.x;
  int h = blk & 63, cc = (blk >> 6) & 7, b = blk >> 9;
  int tid = threadIdx.x, lane = tid & 63, w = tid >> 6, r16 = lane & 15, q = lane >> 4;
  __shared__ __align__(16) float cs_s[CHUNK];
  cs_s[tid] = dacs[((long)(b * NHEADS + h) * NC + cc) * CHUNK + tid];
  __syncthreads();
  const bf16* Cb = Cg + ((long)b * SEQLEN + cc * CHUNK) * D_STATE;
  const bf16* Pb = prevb + (long)blk * (HEADDIM * D_STATE);
  f32x4v zero4 = {0.f, 0.f, 0.f, 0.f};
  f32x4v acc[4][4];
#pragma unroll
  for (int i = 0; i < 4; ++i)
#pragma unroll
    for (int j = 0; j < 4; ++j) acc[i][j] = zero4;
#pragma unroll
  for (int kk = 0; kk < 4; ++kk) {
    bfrag8 bv[4];
#pragma unroll
    for (int pt = 0; pt < 4; ++pt)
      bv[pt] = *(const bfrag8*)(Pb + (long)(pt * 16 + r16) * D_STATE + kk * 32 + q * 8);
#pragma unroll
    for (int lt = 0; lt < 4; ++lt) {
      bfrag8 av = *(const bfrag8*)(Cb + (long)(w * 64 + lt * 16 + r16) * D_STATE + kk * 32 + q * 8);
#pragma unroll
      for (int pt = 0; pt < 4; ++pt) acc[lt][pt] = mfma16(av, bv[pt], acc[lt][pt]);
    }
  }
  bf16* ybase = ybuf + ((long)b * SEQLEN + cc * CHUNK) * D_INNER + h * HEADDIM;
#pragma unroll
  for (int lt = 0; lt < 4; ++lt)
#pragma unroll
    for (int pt = 0; pt < 4; ++pt)
#pragma unroll
      for (int r = 0; r < 4; ++r) {
        int lrow = w * 64 + lt * 16 + q * 4 + r;
        float ef = __expf(cs_s[lrow]);
        bf16* p = ybase + (long)lrow * D_INNER + pt * 16 + r16;
        *p = f2b(b2f(*p) + acc[lt][pt][r] * ef);
      }
}

// ---------------- gate + RMSNorm, in-place ----------------
__global__ __launch_bounds__(256) void gate_norm_kernel(bf16* __restrict__ ybuf,
    const bf16* __restrict__ zb, const float* __restrict__ norm_w) {
  int row = blockIdx.x, tid = threadIdx.x;
  bf16* y = ybuf + (long)row * D_INNER;
  const bf16* z = zb + (long)row * D_INNER;
  float v[16];
  float ss = 0.f;
#pragma unroll
  for (int i = 0; i < 2; ++i) {
    int e = tid * 16 + i * 8;
    bfrag8 yv = *(const bfrag8*)(y + e);
    bfrag8 zv = *(const bfrag8*)(z + e);
#pragma unroll
    for (int j = 0; j < 8; ++j) {
      float a = (float)yv[j] * siluf((float)zv[j]);
      v[i * 8 + j] = a;
      ss += a * a;
    }
  }
#pragma unroll
  for (int off = 32; off > 0; off >>= 1) ss += __shfl_down(ss, off);
  __shared__ __align__(16) float red[4];
  int lane = tid & 63, w = tid >> 6;
  if (lane == 0) red[w] = ss;
  __syncthreads();
  float tot = red[0] + red[1] + red[2] + red[3];
  float scale = rsqrtf(tot * (1.f / D_INNER) + RMS_EPS);
#pragma unroll
  for (int i = 0; i < 2; ++i) {
    int e = tid * 16 + i * 8;
    float4 w0 = *(const float4*)(norm_w + e);
    float4 w1 = *(const float4*)(norm_w + e + 4);
    bfrag8 o;
    o[0] = (__bf16)(v[i * 8 + 0] * scale * w0.x);
    o[1] = (__bf16)(v[i * 8 + 1] * scale * w0.y);
    o[2] = (__bf16)(v[i * 8 + 2] * scale * w0.z);
    o[3] = (__bf16)(v[i * 8 + 3] * scale * w0.w);
    o[4] = (__bf16)(v[i * 8 + 4] * scale * w1.x);
    o[5] = (__bf16)(v[i * 8 + 5] * scale * w1.y);
    o[6] = (__bf16)(v[i * 8 + 6] * scale * w1.z);
    o[7] = (__bf16)(v[i * 8 + 7] * scale * w1.w);
    *(bfrag8*)(y + e) = o;
  }
}

// ---------------- launch ----------------
extern "C" void kernel_launch(void* const* d_in, const int* in_sizes, int n_in,
                              void* d_out, int out_size, void* d_ws, size_t ws_size,
                              hipStream_t stream) {
  if (ws_size < WS_NEEDED) return;

  const float* u       = (const float*)d_in[0];
  const float* w_in    = (const float*)d_in[1];
  const float* conv_w  = (const float*)d_in[2];
  const float* conv_b  = (const float*)d_in[3];
  const float* dt_bias = (const float*)d_in[4];
  const float* A_log   = (const float*)d_in[5];
  const float* Dskip   = (const float*)d_in[6];
  const float* norm_w  = (const float*)d_in[7];
  const float* w_out   = (const float*)d_in[8];
  float* out = (float*)d_out;

  char* ws = (char*)d_ws;
  bf16*  win_bf  = (bf16*)(ws + OFF_WIN);
  bf16*  x_bf    = (bf16*)(ws + OFF_XBF);
  bf16*  prevb   = (bf16*)(ws + OFF_PREV);
  bf16*  wout_bf = (bf16*)(ws + OFF_WOUT);
  bf16*  u_bf    = (bf16*)(ws + OFF_UBF);
  float* dtv     = (float*)(ws + OFF_DTV);
  float* dacs    = (float*)(ws + OFF_DACS);
  bf16*  B_bf    = (bf16*)(ws + OFF_BBF);
  bf16*  C_bf    = (bf16*)(ws + OFF_CBF);
  float* CBb     = (float*)(ws + OFF_CB);
  bf16*  BT_bf   = (bf16*)(ws + OFF_BT);
  bf16*  xbc_bf  = (bf16*)(ws + OFF_XBC);
  float* states  = (float*)(ws + OFF_STATE);
  bf16*  z_bf    = (bf16*)(ws + OFF_ZBF);
  float* dt_raw  = (float*)(ws + OFF_DTRAW);
  bf16*  ybuf    = (bf16*)(ws + OFF_YBUF);

  cast_all_kernel<<<25344, 256, 0, stream>>>(u, w_in, u_bf, win_bf);
  gemm1_kernel<<<1152, 512, 0, stream>>>(u_bf, win_bf, z_bf, xbc_bf, dt_raw);
  dt_scan_kernel<<<1024, 256, 0, stream>>>(dt_raw, dt_bias, A_log, dtv, dacs);
  conv_kernel<<<dim3(17, SEQLEN / 8, 2), 256, 0, stream>>>(xbc_bf, conv_w, conv_b, x_bf, B_bf, C_bf, BT_bf);
  cb_kernel<<<64, 256, 0, stream>>>(C_bf, B_bf, CBb);
  ssm_diag_kernel<<<1024, 256, 0, stream>>>(x_bf, BT_bf, CBb, dtv, dacs, Dskip, ybuf, states);
  state_scan_kernel<<<4096, 256, 0, stream>>>(states, dacs, prevb);
  yoff_kernel<<<1024, 256, 0, stream>>>(C_bf, prevb, dacs, ybuf);
  cast_kernel<<<8192, 256, 0, stream>>>(w_out, wout_bf, (long)D_MODEL * D_INNER / 4);
  gate_norm_kernel<<<ROWSTOT, 256, 0, stream>>>(ybuf, z_bf, norm_w);
  gemm2_kernel<<<256, 512, 0, stream>>>(ybuf, wout_bf, out);
}

// Round 10
// 562.592 us; speedup vs baseline: 1.0623x; 1.0623x over previous
//
#include <hip/hip_runtime.h>
#include <hip/hip_bf16.h>

// Mamba2 layer, MI355X/gfx950. Round 9: gemm2 reverted to 128x128/256t/512blk
// (2 blocks/CU inter-block overlap beats B-reuse at N=2048) + XOR LDS swizzle;
// dt_scan fused into conv launch; w_out cast fused into gate_norm launch.

#define D_MODEL   2048
#define D_STATE   128
#define HEADDIM   64
#define CHUNK     256
#define D_INNER   4096
#define NHEADS    64
#define CONV_DIM  4352
#define D_IN_PROJ 8512
#define SEQLEN    2048
#define NC        8
#define ROWSTOT   4096
#define NPAD      8576
#define RMS_EPS   1e-5f

// ---- workspace layout (byte offsets), lifetime-overlaid ----
// S_A: win_bf(steps 0-1) -> x_bf(2-4) -> prevb(5-6)@+0 ; wout_bf(7-8)@+16MB
#define OFF_WIN   0ull
#define OFF_XBF   0ull
#define OFF_PREV  0ull
#define OFF_WOUT  16777216ull
#define OFF_UBF   35127296ull
#define OFF_DTV   35127296ull
#define OFF_DACS  36175872ull
#define OFF_BBF   37224448ull
#define OFF_CBF   38273024ull
#define OFF_CB    39321600ull
#define OFF_BT    43515904ull
#define OFF_XBC   51904512ull
#define OFF_STATE 51904512ull
#define OFF_ZBF   87556096ull
#define OFF_DTRAW 121110528ull
#define OFF_YBUF  121110528ull
#define WS_NEEDED 154664960ull

// fused-cast segment sizes (float4 units) — u and w_in ONLY
#define N4_U    2097152l
#define N4_WIN  4390912l

typedef __hip_bfloat16 bf16;
typedef __bf16 bfrag8 __attribute__((ext_vector_type(8)));
typedef float  f32x4v __attribute__((ext_vector_type(4)));

__device__ __forceinline__ f32x4v mfma16(bfrag8 a, bfrag8 b, f32x4v c) {
  return __builtin_amdgcn_mfma_f32_16x16x32_bf16(a, b, c, 0, 0, 0);
}

__device__ __forceinline__ void gload_lds16(const void* g, void* l) {
  __builtin_amdgcn_global_load_lds((const __attribute__((address_space(1))) void*)g,
                                   (__attribute__((address_space(3))) void*)l, 16, 0, 0);
}

__device__ __forceinline__ bf16 f2b(float x) { return __float2bfloat16(x); }
__device__ __forceinline__ float b2f(bf16 x) { return __bfloat162float(x); }
__device__ __forceinline__ float siluf(float x) { return x / (1.f + __expf(-x)); }

// ---------------- cast: u -> u_bf, w_in -> win_bf (padded). NOT w_out. ------
__global__ __launch_bounds__(256) void cast_all_kernel(const float* __restrict__ u,
    const float* __restrict__ w_in,
    bf16* __restrict__ u_bf, bf16* __restrict__ win_bf) {
  long i = (long)blockIdx.x * 256 + threadIdx.x;
  if (i < N4_U) {
    float4 v = ((const float4*)u)[i];
    bf16* o = u_bf + i * 4;
    o[0] = f2b(v.x); o[1] = f2b(v.y); o[2] = f2b(v.z); o[3] = f2b(v.w);
  } else if (i < N4_U + N4_WIN) {
    long e = (i - N4_U) * 4;
    long row = e / D_MODEL;
    bf16* o = win_bf + e;
    if (row < D_IN_PROJ) {
      float4 v = *(const float4*)(w_in + e);
      o[0] = f2b(v.x); o[1] = f2b(v.y); o[2] = f2b(v.z); o[3] = f2b(v.w);
    } else {
      bf16 z = f2b(0.f);
      o[0] = z; o[1] = z; o[2] = z; o[3] = z;
    }
  }
}

// LDS swizzle: k-slot q of row r stored at slot q^((r>>1)&3); frag reads use
// (q^((r16>>1)&3))*8. Every bank 8 dwords/wave-instr (2-way = free).

// ---------------- GEMM1: 256x128 tile, 512 threads, BK=64, XCD swizzle ------
__global__ __launch_bounds__(512) void gemm1_kernel(const bf16* __restrict__ A,
                                                    const bf16* __restrict__ B,
                                                    bf16* __restrict__ zb,
                                                    bf16* __restrict__ xbc,
                                                    float* __restrict__ dtraw) {
  int pid = blockIdx.x;
  int t = pid & 63, s = pid >> 6;
  int sm = s / 9, sn = s % 9;
  int xcd = t & 7, j8 = t >> 3;
  int tm = sm * 8 + (xcd >> 1) * 2 + (j8 & 1);
  int tn = sn * 8 + (xcd & 1) * 4 + (j8 >> 1);
  if (tn >= 67) return;
  long row0 = (long)tm * 256, col0 = (long)tn * 128;

  __shared__ __align__(16) bf16 As[2 * 256 * 32];   // 32 KB
  __shared__ __align__(16) bf16 Bs[2 * 128 * 32];   // 16 KB
  int tid = threadIdx.x, lane = tid & 63, w = tid >> 6;
  int wr = w >> 1, wc = w & 1, r16 = lane & 15, q = lane >> 4;
  int qs = (q ^ ((r16 >> 1) & 3)) * 8;              // swizzled frag k-offset
  const int K = D_MODEL;
  f32x4v zero4 = {0.f, 0.f, 0.f, 0.f};
  f32x4v acc[4][4];
#pragma unroll
  for (int i = 0; i < 4; ++i)
#pragma unroll
    for (int j = 0; j < 4; ++j) acc[i][j] = zero4;

  for (int kt = 0; kt < K; kt += 64) {
    __syncthreads();
#pragma unroll
    for (int j = 0; j < 4; ++j) {          // A: 2048 chunks of 16B
      int ci = j * 512 + tid;
      int half = ci >> 10, cj = ci & 1023;
      int r = cj >> 2;
      int ko = half * 32 + ((cj & 3) ^ ((cj >> 3) & 3)) * 8;
      gload_lds16(A + (row0 + r) * (long)K + kt + ko,
                  (char*)As + j * 8192 + w * 1024);            // wave-uniform
    }
#pragma unroll
    for (int j = 0; j < 2; ++j) {          // B: 1024 chunks of 16B
      int ci = j * 512 + tid;
      int half = ci >> 9, cj = ci & 511;
      int r = cj >> 2;
      int ko = half * 32 + ((cj & 3) ^ ((cj >> 3) & 3)) * 8;
      gload_lds16(B + (col0 + r) * (long)K + kt + ko,
                  (char*)Bs + j * 8192 + w * 1024);            // wave-uniform
    }
    __syncthreads();
#pragma unroll
    for (int ks = 0; ks < 2; ++ks) {
      const bf16* Ab = As + ks * 8192;
      const bf16* Bb = Bs + ks * 4096;
      bfrag8 af[4], bfv[4];
#pragma unroll
      for (int i = 0; i < 4; ++i) af[i]  = *(const bfrag8*)(Ab + (wr * 64 + i * 16 + r16) * 32 + qs);
#pragma unroll
      for (int i = 0; i < 4; ++i) bfv[i] = *(const bfrag8*)(Bb + (wc * 64 + i * 16 + r16) * 32 + qs);
#pragma unroll
      for (int i = 0; i < 4; ++i)
#pragma unroll
        for (int j = 0; j < 4; ++j) acc[i][j] = mfma16(af[i], bfv[j], acc[i][j]);
    }
  }
#pragma unroll
  for (int i = 0; i < 4; ++i)
#pragma unroll
    for (int j = 0; j < 4; ++j) {
      long col = col0 + wc * 64 + j * 16 + r16;
#pragma unroll
      for (int r = 0; r < 4; ++r) {
        long row = row0 + wr * 64 + i * 16 + q * 4 + r;
        float v = acc[i][j][r];
        if (col < D_INNER)                       zb[row * D_INNER + col] = f2b(v);
        else if (col < D_INNER + CONV_DIM)       xbc[row * CONV_DIM + (col - D_INNER)] = f2b(v);
        else if (col < D_IN_PROJ)                dtraw[row * NHEADS + (col - D_INNER - CONV_DIM)] = v;
      }
    }
}

// ---------------- GEMM2: 128x128, 256 threads, 512 blocks, XCD + LDS swizzle
__global__ __launch_bounds__(256) void gemm2_kernel(const bf16* __restrict__ A,
                                                    const bf16* __restrict__ B,
                                                    float* __restrict__ C) {
  int pid = blockIdx.x;
  int t = pid & 63, s = pid >> 6;          // tiles 32x16, super grid 4x2
  int sm = s >> 1, sn = s & 1;
  int xcd = t & 7, j8 = t >> 3;
  int tm = sm * 8 + (xcd >> 1) * 2 + (j8 & 1);
  int tn = sn * 8 + (xcd & 1) * 4 + (j8 >> 1);
  long row0 = (long)tm * 128, col0 = (long)tn * 128;

  __shared__ __align__(16) bf16 As[2 * 128 * 32];
  __shared__ __align__(16) bf16 Bs[2 * 128 * 32];
  int tid = threadIdx.x, lane = tid & 63, w = tid >> 6;
  int wr = w >> 1, wc = w & 1, r16 = lane & 15, q = lane >> 4;
  int qs = (q ^ ((r16 >> 1) & 3)) * 8;
  const int K = D_INNER, ldc = D_MODEL;
  f32x4v zero4 = {0.f, 0.f, 0.f, 0.f};
  f32x4v acc[4][4];
#pragma unroll
  for (int i = 0; i < 4; ++i)
#pragma unroll
    for (int j = 0; j < 4; ++j) acc[i][j] = zero4;

  for (int kt = 0; kt < K; kt += 64) {
    __syncthreads();
#pragma unroll
    for (int j = 0; j < 4; ++j) {
      int ci = (j * 4 + w) * 64 + lane;
      int half = ci >> 9, cj = ci & 511;
      int r = cj >> 2;
      int ko = half * 32 + ((cj & 3) ^ ((cj >> 3) & 3)) * 8;
      gload_lds16(A + (row0 + r) * (long)K + kt + ko,
                  (char*)As + (j * 4 + w) * 1024);             // wave-uniform
    }
#pragma unroll
    for (int j = 0; j < 4; ++j) {
      int ci = (j * 4 + w) * 64 + lane;
      int half = ci >> 9, cj = ci & 511;
      int r = cj >> 2;
      int ko = half * 32 + ((cj & 3) ^ ((cj >> 3) & 3)) * 8;
      gload_lds16(B + (col0 + r) * (long)K + kt + ko,
                  (char*)Bs + (j * 4 + w) * 1024);             // wave-uniform
    }
    __syncthreads();
#pragma unroll
    for (int ks = 0; ks < 2; ++ks) {
      const bf16* Ab = As + ks * 4096;
      const bf16* Bb = Bs + ks * 4096;
      bfrag8 af[4], bfv[4];
#pragma unroll
      for (int i = 0; i < 4; ++i) af[i]  = *(const bfrag8*)(Ab + (wr * 64 + i * 16 + r16) * 32 + qs);
#pragma unroll
      for (int i = 0; i < 4; ++i) bfv[i] = *(const bfrag8*)(Bb + (wc * 64 + i * 16 + r16) * 32 + qs);
#pragma unroll
      for (int i = 0; i < 4; ++i)
#pragma unroll
        for (int j = 0; j < 4; ++j) acc[i][j] = mfma16(af[i], bfv[j], acc[i][j]);
    }
  }
#pragma unroll
  for (int i = 0; i < 4; ++i)
#pragma unroll
    for (int j = 0; j < 4; ++j)
#pragma unroll
      for (int r = 0; r < 4; ++r) {
        long row = row0 + wr * 64 + i * 16 + q * 4 + r;
        long col = col0 + wc * 64 + j * 16 + r16;
        C[row * ldc + col] = acc[i][j][r];
      }
}

// ---------------- FUSED: dt softplus+cumsum (blocks 0..1023) + conv (rest) --
__global__ __launch_bounds__(256) void conv_dt_kernel(
    const float* __restrict__ dtraw, const float* __restrict__ dt_bias,
    const float* __restrict__ A_log, float* __restrict__ dtv_buf,
    float* __restrict__ dacs_buf,
    const bf16* __restrict__ xbc, const float* __restrict__ conv_w,
    const float* __restrict__ conv_b, bf16* __restrict__ xo,
    bf16* __restrict__ Bo, bf16* __restrict__ Co, bf16* __restrict__ BT) {
  if (blockIdx.x < 1024) {
    // ---- dt_scan part ----
    int blk = blockIdx.x;
    int c = blk & 7, h = (blk >> 3) & 63, b = blk >> 9;
    int s = threadIdx.x, lane = s & 63, w = s >> 6;
    long row = (long)b * SEQLEN + c * CHUNK + s;
    float raw = dtraw[row * NHEADS + h] + dt_bias[h];
    float dtv = fmaxf(raw, 0.f) + log1pf(__expf(-fabsf(raw)));
    float A = -__expf(A_log[h]);
    float x = dtv * A;
#pragma unroll
    for (int off = 1; off < 64; off <<= 1) {
      float y = __shfl_up(x, off);
      if (lane >= off) x += y;
    }
    __shared__ __align__(16) float wsum[4];
    if (lane == 63) wsum[w] = x;
    __syncthreads();
    float pre = 0.f;
#pragma unroll
    for (int i = 0; i < 4; ++i) pre += (i < w) ? wsum[i] : 0.f;
    long o = ((long)(b * NHEADS + h) * NC + c) * CHUNK + s;
    dtv_buf[o] = dtv;
    dacs_buf[o] = x + pre;
    return;
  }
  // ---- conv part ----
  int t = blockIdx.x - 1024;               // 0..8703
  int bx = t % 17;
  int rest = t / 17;
  int by = rest & 255, bz = rest >> 8;
  int cidx = bx * 256 + threadIdx.x;
  int l0 = by * 8, b = bz;
  float4 wv = *(const float4*)(conv_w + cidx * 4);
  float bias = conv_b[cidx];
  const bf16* base = xbc + (long)b * SEQLEN * CONV_DIM + cidx;
  float win[11];
#pragma unroll
  for (int k = 0; k < 11; ++k) {
    int ls = l0 - 3 + k;
    win[k] = (ls >= 0) ? b2f(base[(long)ls * CONV_DIM]) : 0.f;
  }
  int cgrp = (cidx < D_INNER) ? 0 : ((cidx < D_INNER + D_STATE) ? 1 : 2);
  int n = cidx - D_INNER;
  int n2 = cidx - D_INNER - D_STATE;
  int cch = l0 >> 8;
#pragma unroll
  for (int j = 0; j < 8; ++j) {
    float acc = bias + wv.x * win[j] + wv.y * win[j + 1] + wv.z * win[j + 2] + wv.w * win[j + 3];
    bf16 o = f2b(siluf(acc));
    int l = l0 + j;
    long rowo = (long)b * SEQLEN + l;
    if (cgrp == 0) {
      xo[rowo * D_INNER + cidx] = o;
    } else if (cgrp == 1) {
      Bo[rowo * D_STATE + n] = o;
      BT[(((long)b * NC + cch) * D_STATE + n) * CHUNK + (l & 255)] = o;
    } else {
      Co[rowo * D_STATE + n2] = o;
    }
  }
}

// ---------------- CB[l,s] per (b,chunk), 4 st-tiles per block ----------------
__global__ __launch_bounds__(256) void cb_kernel(const bf16* __restrict__ Cg,
                                                 const bf16* __restrict__ Bg,
                                                 float* __restrict__ CB) {
  int blk = blockIdx.x;
  int stile = blk & 3, bc = blk >> 2;
  int c = bc & 7, b = bc >> 3;
  int tid = threadIdx.x, lane = tid & 63, w = tid >> 6, r16 = lane & 15, q = lane >> 4;
  const bf16* Cb = Cg + ((long)b * SEQLEN + c * CHUNK) * D_STATE;
  const bf16* Bb = Bg + ((long)b * SEQLEN + c * CHUNK) * D_STATE;
  bfrag8 af[4][4];
#pragma unroll
  for (int lt = 0; lt < 4; ++lt)
#pragma unroll
    for (int kk = 0; kk < 4; ++kk)
      af[lt][kk] = *(const bfrag8*)(Cb + (long)(w * 64 + lt * 16 + r16) * D_STATE + kk * 32 + q * 8);
  float* CBb = CB + (long)bc * CHUNK * CHUNK;
  f32x4v zero4 = {0.f, 0.f, 0.f, 0.f};
  for (int st = stile * 4; st < stile * 4 + 4; ++st) {
    f32x4v acc[4] = {zero4, zero4, zero4, zero4};
#pragma unroll
    for (int kk = 0; kk < 4; ++kk) {
      bfrag8 bfv = *(const bfrag8*)(Bb + (long)(st * 16 + r16) * D_STATE + kk * 32 + q * 8);
#pragma unroll
      for (int lt = 0; lt < 4; ++lt) acc[lt] = mfma16(af[lt][kk], bfv, acc[lt]);
    }
#pragma unroll
    for (int lt = 0; lt < 4; ++lt)
#pragma unroll
      for (int r = 0; r < 4; ++r)
        CBb[(long)(w * 64 + lt * 16 + q * 4 + r) * CHUNK + st * 16 + r16] = acc[lt][r];
  }
}

// ---------------- per (b,chunk,head): Y_diag + skip, chunk states ------------
__global__ __launch_bounds__(256) void ssm_diag_kernel(
    const bf16* __restrict__ xg, const bf16* __restrict__ BT,
    const float* __restrict__ CB, const float* __restrict__ dtv_buf,
    const float* __restrict__ dacs_buf, const float* __restrict__ Dskip,
    bf16* __restrict__ ybuf, float* __restrict__ states) {
  int blk = blockIdx.x;
  int h = blk & 63, cc = (blk >> 6) & 7, b = blk >> 9;
  int tid = threadIdx.x, lane = tid & 63, w = tid >> 6, r16 = lane & 15, q = lane >> 4;

  __shared__ __align__(16) __bf16 xT[HEADDIM][264];
  __shared__ __align__(16) float cs_s[CHUNK];
  __shared__ __align__(16) float dt_s[CHUNK];
  __shared__ __align__(16) float w_s[CHUNK];

  long hco = ((long)(b * NHEADS + h) * NC + cc) * CHUNK;
  cs_s[tid] = dacs_buf[hco + tid];
  dt_s[tid] = dtv_buf[hco + tid];
  __syncthreads();
  float cl_last = cs_s[CHUNK - 1];
  w_s[tid] = __expf(cl_last - cs_s[tid]) * dt_s[tid];

  const __bf16* xbase = (const __bf16*)(xg + ((long)b * SEQLEN + cc * CHUNK) * D_INNER + h * HEADDIM);
#pragma unroll
  for (int it = 0; it < 8; ++it) {
    int e = it * 256 + tid;
    int s = e >> 3, p0 = (e & 7) * 8;
    bfrag8 xv = *(const bfrag8*)(xbase + (long)s * D_INNER + p0);
#pragma unroll
    for (int j = 0; j < 8; ++j) xT[p0 + j][s] = xv[j];
  }
  __syncthreads();

  const float* CBchunk = CB + (long)(b * NC + cc) * CHUNK * CHUNK;
  const __bf16* BTc = (const __bf16*)(BT + (((long)b * NC + cc) * D_STATE) * CHUNK);
  f32x4v zero4 = {0.f, 0.f, 0.f, 0.f};
  f32x4v accY[4][4], accS[2][4];
#pragma unroll
  for (int i = 0; i < 4; ++i)
#pragma unroll
    for (int j = 0; j < 4; ++j) accY[i][j] = zero4;
#pragma unroll
  for (int i = 0; i < 2; ++i)
#pragma unroll
    for (int j = 0; j < 4; ++j) accS[i][j] = zero4;

  int l_row[4];
  const float* CBrow[4];
#pragma unroll
  for (int lt = 0; lt < 4; ++lt) {
    l_row[lt] = w * 64 + lt * 16 + r16;
    CBrow[lt] = CBchunk + (long)l_row[lt] * CHUNK;
  }

#pragma unroll 2
  for (int ks = 0; ks < 8; ++ks) {
    int s0 = ks * 32 + q * 8;
    float4 cs0 = *(const float4*)(cs_s + s0);
    float4 cs1 = *(const float4*)(cs_s + s0 + 4);
    float4 dt0 = *(const float4*)(dt_s + s0);
    float4 dt1 = *(const float4*)(dt_s + s0 + 4);
    float4 w0  = *(const float4*)(w_s + s0);
    float4 w1  = *(const float4*)(w_s + s0 + 4);
    float csv[8] = {cs0.x, cs0.y, cs0.z, cs0.w, cs1.x, cs1.y, cs1.z, cs1.w};
    float dtv8[8] = {dt0.x, dt0.y, dt0.z, dt0.w, dt1.x, dt1.y, dt1.z, dt1.w};
    float wv8[8]  = {w0.x, w0.y, w0.z, w0.w, w1.x, w1.y, w1.z, w1.w};

    bfrag8 xf[4];
#pragma unroll
    for (int pt = 0; pt < 4; ++pt) xf[pt] = *(const bfrag8*)(&xT[pt * 16 + r16][s0]);

#pragma unroll
    for (int lt = 0; lt < 4; ++lt) {
      int l = l_row[lt];
      float cs_l = cs_s[l];
      float4 cb0 = *(const float4*)(CBrow[lt] + s0);
      float4 cb1 = *(const float4*)(CBrow[lt] + s0 + 4);
      float cbv[8] = {cb0.x, cb0.y, cb0.z, cb0.w, cb1.x, cb1.y, cb1.z, cb1.w};
      bfrag8 pf;
#pragma unroll
      for (int j = 0; j < 8; ++j) {
        float v = (s0 + j <= l)
                    ? cbv[j] * __expf(fminf(cs_l - csv[j], 0.f)) * dtv8[j]
                    : 0.f;
        pf[j] = (__bf16)v;
      }
#pragma unroll
      for (int pt = 0; pt < 4; ++pt) accY[lt][pt] = mfma16(pf, xf[pt], accY[lt][pt]);
    }

#pragma unroll
    for (int nt = 0; nt < 2; ++nt) {
      int n = w * 32 + nt * 16 + r16;
      bfrag8 braw = *(const bfrag8*)(BTc + (long)n * CHUNK + s0);
      bfrag8 bwf;
#pragma unroll
      for (int j = 0; j < 8; ++j) bwf[j] = (__bf16)((float)braw[j] * wv8[j]);
#pragma unroll
      for (int pt = 0; pt < 4; ++pt) accS[nt][pt] = mfma16(bwf, xf[pt], accS[nt][pt]);
    }
  }

  float dsk = Dskip[h];
  bf16* ybase = ybuf + ((long)b * SEQLEN + cc * CHUNK) * D_INNER + h * HEADDIM;
#pragma unroll
  for (int lt = 0; lt < 4; ++lt)
#pragma unroll
    for (int pt = 0; pt < 4; ++pt)
#pragma unroll
      for (int r = 0; r < 4; ++r) {
        int lrow = w * 64 + lt * 16 + q * 4 + r;
        int pcol = pt * 16 + r16;
        ybase[(long)lrow * D_INNER + pcol] = f2b(accY[lt][pt][r] + (float)xT[pcol][lrow] * dsk);
      }
  float* sbase = states + (long)blk * (HEADDIM * D_STATE);
#pragma unroll
  for (int nt = 0; nt < 2; ++nt)
#pragma unroll
    for (int pt = 0; pt < 4; ++pt)
#pragma unroll
      for (int r = 0; r < 4; ++r)
        sbase[(long)(pt * 16 + r16) * D_STATE + w * 32 + nt * 16 + q * 4 + r] = accS[nt][pt][r];
}

// ---------------- inter-chunk state scan (e-parallel grid) ----------------
__global__ __launch_bounds__(256) void state_scan_kernel(const float* __restrict__ states,
    const float* __restrict__ dacs, bf16* __restrict__ prevb) {
  int gid = blockIdx.x;
  int et = gid & 31, bh = gid >> 5;
  int h = bh & 63, b = bh >> 6;
  int e = et * 256 + threadIdx.x;
  float dec[NC];
#pragma unroll
  for (int c = 0; c < NC; ++c)
    dec[c] = __expf(dacs[((long)(b * NHEADS + h) * NC + c) * CHUNK + (CHUNK - 1)]);
  float carry = 0.f;
#pragma unroll
  for (int c = 0; c < NC; ++c) {
    long off = ((long)((b * NC + c) * NHEADS + h)) * (HEADDIM * D_STATE) + e;
    prevb[off] = f2b(carry);
    carry = carry * dec[c] + states[off];
  }
}

// ---------------- Y_off accumulate (bf16 RMW) ----------------
__global__ __launch_bounds__(256) void yoff_kernel(const bf16* __restrict__ Cg,
    const bf16* __restrict__ prevb, const float* __restrict__ dacs,
    bf16* __restrict__ ybuf) {
  int blk = blockIdx.x;
  int h = blk & 63, cc = (blk >> 6) & 7, b = blk >> 9;
  int tid = threadIdx.x, lane = tid & 63, w = tid >> 6, r16 = lane & 15, q = lane >> 4;
  __shared__ __align__(16) float cs_s[CHUNK];
  cs_s[tid] = dacs[((long)(b * NHEADS + h) * NC + cc) * CHUNK + tid];
  __syncthreads();
  const bf16* Cb = Cg + ((long)b * SEQLEN + cc * CHUNK) * D_STATE;
  const bf16* Pb = prevb + (long)blk * (HEADDIM * D_STATE);
  f32x4v zero4 = {0.f, 0.f, 0.f, 0.f};
  f32x4v acc[4][4];
#pragma unroll
  for (int i = 0; i < 4; ++i)
#pragma unroll
    for (int j = 0; j < 4; ++j) acc[i][j] = zero4;
#pragma unroll
  for (int kk = 0; kk < 4; ++kk) {
    bfrag8 bv[4];
#pragma unroll
    for (int pt = 0; pt < 4; ++pt)
      bv[pt] = *(const bfrag8*)(Pb + (long)(pt * 16 + r16) * D_STATE + kk * 32 + q * 8);
#pragma unroll
    for (int lt = 0; lt < 4; ++lt) {
      bfrag8 av = *(const bfrag8*)(Cb + (long)(w * 64 + lt * 16 + r16) * D_STATE + kk * 32 + q * 8);
#pragma unroll
      for (int pt = 0; pt < 4; ++pt) acc[lt][pt] = mfma16(av, bv[pt], acc[lt][pt]);
    }
  }
  bf16* ybase = ybuf + ((long)b * SEQLEN + cc * CHUNK) * D_INNER + h * HEADDIM;
#pragma unroll
  for (int lt = 0; lt < 4; ++lt)
#pragma unroll
    for (int pt = 0; pt < 4; ++pt)
#pragma unroll
      for (int r = 0; r < 4; ++r) {
        int lrow = w * 64 + lt * 16 + q * 4 + r;
        float ef = __expf(cs_s[lrow]);
        bf16* p = ybase + (long)lrow * D_INNER + pt * 16 + r16;
        *p = f2b(b2f(*p) + acc[lt][pt][r] * ef);
      }
}

// ---------------- FUSED: w_out cast (blocks 0..8191) + gate+RMSNorm (rest) --
__global__ __launch_bounds__(256) void cast_gate_kernel(
    const float* __restrict__ w_out, bf16* __restrict__ wout_bf,
    bf16* __restrict__ ybuf, const bf16* __restrict__ zb,
    const float* __restrict__ norm_w) {
  if (blockIdx.x < 8192) {
    long i = (long)blockIdx.x * 256 + threadIdx.x;
    float4 v = ((const float4*)w_out)[i];
    bf16* o = wout_bf + i * 4;
    o[0] = f2b(v.x); o[1] = f2b(v.y); o[2] = f2b(v.z); o[3] = f2b(v.w);
    return;
  }
  int row = blockIdx.x - 8192, tid = threadIdx.x;
  bf16* y = ybuf + (long)row * D_INNER;
  const bf16* z = zb + (long)row * D_INNER;
  float v[16];
  float ss = 0.f;
#pragma unroll
  for (int i = 0; i < 2; ++i) {
    int e = tid * 16 + i * 8;
    bfrag8 yv = *(const bfrag8*)(y + e);
    bfrag8 zv = *(const bfrag8*)(z + e);
#pragma unroll
    for (int j = 0; j < 8; ++j) {
      float a = (float)yv[j] * siluf((float)zv[j]);
      v[i * 8 + j] = a;
      ss += a * a;
    }
  }
#pragma unroll
  for (int off = 32; off > 0; off >>= 1) ss += __shfl_down(ss, off);
  __shared__ __align__(16) float red[4];
  int lane = tid & 63, w = tid >> 6;
  if (lane == 0) red[w] = ss;
  __syncthreads();
  float tot = red[0] + red[1] + red[2] + red[3];
  float scale = rsqrtf(tot * (1.f / D_INNER) + RMS_EPS);
#pragma unroll
  for (int i = 0; i < 2; ++i) {
    int e = tid * 16 + i * 8;
    float4 w0 = *(const float4*)(norm_w + e);
    float4 w1 = *(const float4*)(norm_w + e + 4);
    bfrag8 o;
    o[0] = (__bf16)(v[i * 8 + 0] * scale * w0.x);
    o[1] = (__bf16)(v[i * 8 + 1] * scale * w0.y);
    o[2] = (__bf16)(v[i * 8 + 2] * scale * w0.z);
    o[3] = (__bf16)(v[i * 8 + 3] * scale * w0.w);
    o[4] = (__bf16)(v[i * 8 + 4] * scale * w1.x);
    o[5] = (__bf16)(v[i * 8 + 5] * scale * w1.y);
    o[6] = (__bf16)(v[i * 8 + 6] * scale * w1.z);
    o[7] = (__bf16)(v[i * 8 + 7] * scale * w1.w);
    *(bfrag8*)(y + e) = o;
  }
}

// ---------------- launch ----------------
extern "C" void kernel_launch(void* const* d_in, const int* in_sizes, int n_in,
                              void* d_out, int out_size, void* d_ws, size_t ws_size,
                              hipStream_t stream) {
  if (ws_size < WS_NEEDED) return;

  const float* u       = (const float*)d_in[0];
  const float* w_in    = (const float*)d_in[1];
  const float* conv_w  = (const float*)d_in[2];
  const float* conv_b  = (const float*)d_in[3];
  const float* dt_bias = (const float*)d_in[4];
  const float* A_log   = (const float*)d_in[5];
  const float* Dskip   = (const float*)d_in[6];
  const float* norm_w  = (const float*)d_in[7];
  const float* w_out   = (const float*)d_in[8];
  float* out = (float*)d_out;

  char* ws = (char*)d_ws;
  bf16*  win_bf  = (bf16*)(ws + OFF_WIN);
  bf16*  x_bf    = (bf16*)(ws + OFF_XBF);
  bf16*  prevb   = (bf16*)(ws + OFF_PREV);
  bf16*  wout_bf = (bf16*)(ws + OFF_WOUT);
  bf16*  u_bf    = (bf16*)(ws + OFF_UBF);
  float* dtv     = (float*)(ws + OFF_DTV);
  float* dacs    = (float*)(ws + OFF_DACS);
  bf16*  B_bf    = (bf16*)(ws + OFF_BBF);
  bf16*  C_bf    = (bf16*)(ws + OFF_CBF);
  float* CBb     = (float*)(ws + OFF_CB);
  bf16*  BT_bf   = (bf16*)(ws + OFF_BT);
  bf16*  xbc_bf  = (bf16*)(ws + OFF_XBC);
  float* states  = (float*)(ws + OFF_STATE);
  bf16*  z_bf    = (bf16*)(ws + OFF_ZBF);
  float* dt_raw  = (float*)(ws + OFF_DTRAW);
  bf16*  ybuf    = (bf16*)(ws + OFF_YBUF);

  cast_all_kernel<<<25344, 256, 0, stream>>>(u, w_in, u_bf, win_bf);
  gemm1_kernel<<<1152, 512, 0, stream>>>(u_bf, win_bf, z_bf, xbc_bf, dt_raw);
  conv_dt_kernel<<<9728, 256, 0, stream>>>(dt_raw, dt_bias, A_log, dtv, dacs,
                                           xbc_bf, conv_w, conv_b, x_bf, B_bf, C_bf, BT_bf);
  cb_kernel<<<64, 256, 0, stream>>>(C_bf, B_bf, CBb);
  ssm_diag_kernel<<<1024, 256, 0, stream>>>(x_bf, BT_bf, CBb, dtv, dacs, Dskip, ybuf, states);
  state_scan_kernel<<<4096, 256, 0, stream>>>(states, dacs, prevb);
  yoff_kernel<<<1024, 256, 0, stream>>>(C_bf, prevb, dacs, ybuf);
  cast_gate_kernel<<<12288, 256, 0, stream>>>(w_out, wout_bf, ybuf, z_bf, norm_w);
  gemm2_kernel<<<512, 256, 0, stream>>>(ybuf, wout_bf, out);
}